// Round 1
// baseline (279.244 us; speedup 1.0000x reference)
//
#include <hip/hip_runtime.h>

#define N_ATOMS 100000
#define N_EDGES 625000
#define N_MOL   1000
#define EMB_ATOM 256
#define EMB_EDGE 128

// One 64-lane wave per atom row. Lane i loads float4 at offset i*4 (256 floats
// total, 1024B coalesced per wave). Butterfly reduce, lane 0 atomicAdd to y.
__global__ __launch_bounds__(256) void energy_kernel(
    const float* __restrict__ h_energy,
    const int*   __restrict__ batch_idx,
    const float* __restrict__ W_energy,
    float*       __restrict__ y_out)
{
    const int gid  = blockIdx.x * blockDim.x + threadIdx.x;
    const int atom = gid >> 6;
    const int lane = threadIdx.x & 63;
    if (atom >= N_ATOMS) return;

    const float4* row = reinterpret_cast<const float4*>(h_energy + (size_t)atom * EMB_ATOM);
    const float4* w   = reinterpret_cast<const float4*>(W_energy);
    float4 a = row[lane];
    float4 b = w[lane];
    float s = a.x * b.x + a.y * b.y + a.z * b.z + a.w * b.w;

    #pragma unroll
    for (int m = 32; m >= 1; m >>= 1) s += __shfl_xor(s, m, 64);

    if (lane == 0) atomicAdd(&y_out[batch_idx[atom]], s);
}

// One 64-lane wave per edge row. Lane i loads float2 (128 floats, 512B
// coalesced). Butterfly reduce (all lanes get sum), lanes 0..2 scatter
// s*V_st[e][c] into force[idx_t[e]][c].
__global__ __launch_bounds__(256) void forces_kernel(
    const float* __restrict__ h_forces,
    const float* __restrict__ V_st,
    const int*   __restrict__ idx_t,
    const float* __restrict__ W_forces,
    const float* __restrict__ b_forces,
    float*       __restrict__ force_out)
{
    const int gid  = blockIdx.x * blockDim.x + threadIdx.x;
    const int edge = gid >> 6;
    const int lane = threadIdx.x & 63;
    if (edge >= N_EDGES) return;

    const float2* row = reinterpret_cast<const float2*>(h_forces + (size_t)edge * EMB_EDGE);
    const float2* w   = reinterpret_cast<const float2*>(W_forces);
    float2 a = row[lane];
    float2 b = w[lane];
    float s = a.x * b.x + a.y * b.y;

    #pragma unroll
    for (int m = 32; m >= 1; m >>= 1) s += __shfl_xor(s, m, 64);

    s += b_forces[0];

    if (lane < 3) {
        float f = s * V_st[(size_t)edge * 3 + lane];
        atomicAdd(&force_out[(size_t)idx_t[edge] * 3 + lane], f);
    }
}

extern "C" void kernel_launch(void* const* d_in, const int* in_sizes, int n_in,
                              void* d_out, int out_size, void* d_ws, size_t ws_size,
                              hipStream_t stream) {
    const float* h_energy  = (const float*)d_in[0];
    const float* h_forces  = (const float*)d_in[1];
    const float* V_st      = (const float*)d_in[2];
    const int*   idx_t     = (const int*)d_in[3];
    const int*   batch_idx = (const int*)d_in[4];
    const float* W_energy  = (const float*)d_in[5];
    const float* W_forces  = (const float*)d_in[6];
    const float* b_forces  = (const float*)d_in[7];

    float* y_out     = (float*)d_out;            // N_MOL floats
    float* force_out = (float*)d_out + N_MOL;    // N_ATOMS*3 floats

    // Both outputs accumulate via atomics — zero them first.
    hipMemsetAsync(d_out, 0, (size_t)out_size * sizeof(float), stream);

    // Energy: 100000 waves, 4 waves/block -> 25000 blocks (exact).
    energy_kernel<<<N_ATOMS / 4, 256, 0, stream>>>(h_energy, batch_idx, W_energy, y_out);

    // Forces: 625000 waves, 4 waves/block -> 156250 blocks (exact).
    forces_kernel<<<N_EDGES / 4, 256, 0, stream>>>(h_forces, V_st, idx_t, W_forces,
                                                   b_forces, force_out);
}

// Round 2
// 268.070 us; speedup vs baseline: 1.0417x; 1.0417x over previous
//
#include <hip/hip_runtime.h>

#define N_ATOMS 100000
#define N_EDGES 625000
#define N_MOL   1000
#define EMB_ATOM 256
#define EMB_EDGE 128

// Vectorized zero of d_out (out_size floats, divisible by 4 here: 301000/4).
__global__ __launch_bounds__(256) void zero_kernel(float4* __restrict__ p, int n4)
{
    const int i = blockIdx.x * blockDim.x + threadIdx.x;
    if (i < n4) p[i] = make_float4(0.f, 0.f, 0.f, 0.f);
}

// One 64-lane wave per atom row. Lane i loads float4 at offset i*4 (256 floats
// total, 1024B coalesced per wave). Butterfly reduce, lane 0 atomicAdd to y.
__global__ __launch_bounds__(256) void energy_kernel(
    const float* __restrict__ h_energy,
    const int*   __restrict__ batch_idx,
    const float* __restrict__ W_energy,
    float*       __restrict__ y_out)
{
    const int gid  = blockIdx.x * blockDim.x + threadIdx.x;
    const int atom = gid >> 6;
    const int lane = threadIdx.x & 63;
    if (atom >= N_ATOMS) return;

    const float4* row = reinterpret_cast<const float4*>(h_energy + (size_t)atom * EMB_ATOM);
    const float4* w   = reinterpret_cast<const float4*>(W_energy);
    float4 a = row[lane];
    float4 b = w[lane];
    float s = a.x * b.x + a.y * b.y + a.z * b.z + a.w * b.w;

    #pragma unroll
    for (int m = 32; m >= 1; m >>= 1) s += __shfl_xor(s, m, 64);

    if (lane == 0) atomicAdd(&y_out[batch_idx[atom]], s);
}

// One 64-lane wave per edge row. Lane i loads float2 (128 floats, 512B
// coalesced). Butterfly reduce (all lanes get sum), lanes 0..2 scatter
// s*V_st[e][c] into force[idx_t[e]][c].
__global__ __launch_bounds__(256) void forces_kernel(
    const float* __restrict__ h_forces,
    const float* __restrict__ V_st,
    const int*   __restrict__ idx_t,
    const float* __restrict__ W_forces,
    const float* __restrict__ b_forces,
    float*       __restrict__ force_out)
{
    const int gid  = blockIdx.x * blockDim.x + threadIdx.x;
    const int edge = gid >> 6;
    const int lane = threadIdx.x & 63;
    if (edge >= N_EDGES) return;

    const float2* row = reinterpret_cast<const float2*>(h_forces + (size_t)edge * EMB_EDGE);
    const float2* w   = reinterpret_cast<const float2*>(W_forces);
    float2 a = row[lane];
    float2 b = w[lane];
    float s = a.x * b.x + a.y * b.y;

    #pragma unroll
    for (int m = 32; m >= 1; m >>= 1) s += __shfl_xor(s, m, 64);

    s += b_forces[0];

    if (lane < 3) {
        float f = s * V_st[(size_t)edge * 3 + lane];
        atomicAdd(&force_out[(size_t)idx_t[edge] * 3 + lane], f);
    }
}

extern "C" void kernel_launch(void* const* d_in, const int* in_sizes, int n_in,
                              void* d_out, int out_size, void* d_ws, size_t ws_size,
                              hipStream_t stream) {
    const float* h_energy  = (const float*)d_in[0];
    const float* h_forces  = (const float*)d_in[1];
    const float* V_st      = (const float*)d_in[2];
    const int*   idx_t     = (const int*)d_in[3];
    const int*   batch_idx = (const int*)d_in[4];
    const float* W_energy  = (const float*)d_in[5];
    const float* W_forces  = (const float*)d_in[6];
    const float* b_forces  = (const float*)d_in[7];

    float* y_out     = (float*)d_out;            // N_MOL floats
    float* force_out = (float*)d_out + N_MOL;    // N_ATOMS*3 floats

    // Zero d_out with our own kernel — hipMemsetAsync's fill kernel took
    // 191 us for 1.2 MB under graph replay (R1 rocprof).
    const int n4 = out_size / 4;            // 301000/4 = 75250 exactly
    zero_kernel<<<(n4 + 255) / 256, 256, 0, stream>>>((float4*)d_out, n4);

    // Energy: 100000 waves, 4 waves/block -> 25000 blocks (exact).
    energy_kernel<<<N_ATOMS / 4, 256, 0, stream>>>(h_energy, batch_idx, W_energy, y_out);

    // Forces: 625000 waves, 4 waves/block -> 156250 blocks (exact).
    forces_kernel<<<N_EDGES / 4, 256, 0, stream>>>(h_forces, V_st, idx_t, W_forces,
                                                   b_forces, force_out);
}

// Round 5
// 219.975 us; speedup vs baseline: 1.2694x; 1.2186x over previous
//
#include <hip/hip_runtime.h>

#define N_ATOMS 100000
#define N_EDGES 625000
#define N_MOL   1000
#define EMB_ATOM 256
#define EMB_EDGE 128

typedef float f32x4 __attribute__((ext_vector_type(4)));

// Vectorized zero of d_out (out_size floats; 301000 = 75250 float4 exactly).
__global__ __launch_bounds__(256) void zero_kernel(f32x4* __restrict__ p, int n4)
{
    const int i = blockIdx.x * blockDim.x + threadIdx.x;
    if (i < n4) p[i] = (f32x4)(0.f, 0.f, 0.f, 0.f);
}

// One 64-lane wave per atom row. Lane i loads f32x4 at offset i*4 (256 floats
// total, 1024B coalesced per wave). Butterfly reduce, lane 0 atomicAdd to y.
// h_energy is stream-once -> non-temporal loads.
__global__ __launch_bounds__(256) void energy_kernel(
    const float* __restrict__ h_energy,
    const int*   __restrict__ batch_idx,
    const float* __restrict__ W_energy,
    float*       __restrict__ y_out)
{
    const int gid  = blockIdx.x * blockDim.x + threadIdx.x;
    const int atom = gid >> 6;
    const int lane = threadIdx.x & 63;
    if (atom >= N_ATOMS) return;

    const f32x4* row = reinterpret_cast<const f32x4*>(h_energy + (size_t)atom * EMB_ATOM);
    const f32x4* w   = reinterpret_cast<const f32x4*>(W_energy);
    f32x4 a = __builtin_nontemporal_load(row + lane);
    f32x4 b = w[lane];
    float s = a.x * b.x + a.y * b.y + a.z * b.z + a.w * b.w;

    #pragma unroll
    for (int m = 32; m >= 1; m >>= 1) s += __shfl_xor(s, m, 64);

    if (lane == 0) atomicAdd(&y_out[batch_idx[atom]], s);
}

// One 64-lane wave per TWO edges. Lanes 0-31 own edge e0, lanes 32-63 edge e1.
// Each lane loads one f32x4 (16B/lane, 512B/edge contiguous). Butterfly
// reduce within each 32-lane half (xor masks 1..16 never cross bit 5).
// Lanes {0,1,2} / {32,33,34} scatter s*V_st into force[idx_t[e]].
__global__ __launch_bounds__(256) void forces_kernel(
    const float* __restrict__ h_forces,
    const float* __restrict__ V_st,
    const int*   __restrict__ idx_t,
    const float* __restrict__ W_forces,
    const float* __restrict__ b_forces,
    float*       __restrict__ force_out)
{
    const int gid  = blockIdx.x * blockDim.x + threadIdx.x;
    const int wave = gid >> 6;
    const int lane = threadIdx.x & 63;
    const int edge = wave * 2 + (lane >> 5);   // < N_EDGES always (625000 even)
    const int l    = lane & 31;

    const f32x4* row = reinterpret_cast<const f32x4*>(h_forces + (size_t)edge * EMB_EDGE);
    const f32x4* w   = reinterpret_cast<const f32x4*>(W_forces);
    f32x4 a = __builtin_nontemporal_load(row + l);
    f32x4 b = w[l];
    float s = a.x * b.x + a.y * b.y + a.z * b.z + a.w * b.w;

    #pragma unroll
    for (int m = 16; m >= 1; m >>= 1) s += __shfl_xor(s, m, 64);

    s += b_forces[0];

    if (l < 3) {
        float f = s * V_st[(size_t)edge * 3 + l];
        atomicAdd(&force_out[(size_t)idx_t[edge] * 3 + l], f);
    }
}

extern "C" void kernel_launch(void* const* d_in, const int* in_sizes, int n_in,
                              void* d_out, int out_size, void* d_ws, size_t ws_size,
                              hipStream_t stream) {
    const float* h_energy  = (const float*)d_in[0];
    const float* h_forces  = (const float*)d_in[1];
    const float* V_st      = (const float*)d_in[2];
    const int*   idx_t     = (const int*)d_in[3];
    const int*   batch_idx = (const int*)d_in[4];
    const float* W_energy  = (const float*)d_in[5];
    const float* W_forces  = (const float*)d_in[6];
    const float* b_forces  = (const float*)d_in[7];

    float* y_out     = (float*)d_out;            // N_MOL floats
    float* force_out = (float*)d_out + N_MOL;    // N_ATOMS*3 floats

    // Zero d_out (atomic accumulation needs zeroed output each call).
    const int n4 = out_size / 4;                 // 75250 exactly
    zero_kernel<<<(n4 + 255) / 256, 256, 0, stream>>>((f32x4*)d_out, n4);

    // Forces first (long pole): 312500 waves (2 edges each), 4 waves/block.
    forces_kernel<<<N_EDGES / 8, 256, 0, stream>>>(h_forces, V_st, idx_t, W_forces,
                                                   b_forces, force_out);

    // Energy: 100000 waves, 4 waves/block -> 25000 blocks (exact).
    energy_kernel<<<N_ATOMS / 4, 256, 0, stream>>>(h_energy, batch_idx, W_energy, y_out);
}

// Round 7
// 160.845 us; speedup vs baseline: 1.7361x; 1.3676x over previous
//
#include <hip/hip_runtime.h>

#define N_ATOMS 100000
#define N_EDGES 625000
#define N_MOL   1000
#define EMB_ATOM 256
#define EMB_EDGE 128

typedef float f32x4 __attribute__((ext_vector_type(4)));

__device__ __forceinline__ float dot4(f32x4 a, f32x4 b) {
    return a.x * b.x + a.y * b.y + a.z * b.z + a.w * b.w;
}

// Vectorized zero of d_out (301000 floats = 75250 f32x4 exactly).
__global__ __launch_bounds__(256) void zero_kernel(f32x4* __restrict__ p, int n4)
{
    const int i = blockIdx.x * blockDim.x + threadIdx.x;
    if (i < n4) p[i] = (f32x4)(0.f, 0.f, 0.f, 0.f);
}

// One 64-lane wave per FOUR atoms. Lane loads one f32x4 from each of 4
// consecutive rows (4 independent 16B NT loads in flight -> 64B/thread).
// Each row-load instruction covers 1KB contiguous across the wave.
// 25000 waves exactly (100000/4): 6250 blocks x 4 waves x 4 atoms.
__global__ __launch_bounds__(256) void energy_kernel(
    const float* __restrict__ h_energy,
    const int*   __restrict__ batch_idx,
    const float* __restrict__ W_energy,
    float*       __restrict__ y_out)
{
    const int gid   = blockIdx.x * blockDim.x + threadIdx.x;
    const int wave  = gid >> 6;
    const int lane  = threadIdx.x & 63;
    const int atom0 = wave * 4;          // always <= 99996

    const f32x4* w    = reinterpret_cast<const f32x4*>(W_energy);
    const f32x4* base = reinterpret_cast<const f32x4*>(h_energy); // row = 64 x f32x4

    f32x4 b  = w[lane];
    f32x4 a0 = __builtin_nontemporal_load(base + (size_t)(atom0 + 0) * 64 + lane);
    f32x4 a1 = __builtin_nontemporal_load(base + (size_t)(atom0 + 1) * 64 + lane);
    f32x4 a2 = __builtin_nontemporal_load(base + (size_t)(atom0 + 2) * 64 + lane);
    f32x4 a3 = __builtin_nontemporal_load(base + (size_t)(atom0 + 3) * 64 + lane);

    float s0 = dot4(a0, b);
    float s1 = dot4(a1, b);
    float s2 = dot4(a2, b);
    float s3 = dot4(a3, b);

    #pragma unroll
    for (int m = 32; m >= 1; m >>= 1) {
        s0 += __shfl_xor(s0, m, 64);
        s1 += __shfl_xor(s1, m, 64);
        s2 += __shfl_xor(s2, m, 64);
        s3 += __shfl_xor(s3, m, 64);
    }

    if (lane == 0) {
        atomicAdd(&y_out[batch_idx[atom0 + 0]], s0);
        atomicAdd(&y_out[batch_idx[atom0 + 1]], s1);
        atomicAdd(&y_out[batch_idx[atom0 + 2]], s2);
        atomicAdd(&y_out[batch_idx[atom0 + 3]], s3);
    }
}

// One 32-lane half-wave per FOUR consecutive edges (4 independent 16B NT
// loads per thread). Each row-load covers 512B contiguous per half-wave,
// consecutive half-waves cover consecutive 2KB. Butterfly reduce within the
// 32-lane half (masks 1..16 stay inside the half). Lanes 0..2 of each half
// scatter 3 components x 4 edges via atomicAdd.
// Half-waves needed: 625000/4 = 156250; 8 per block -> 19532 blocks (tail
// block has 6 active half-waves, guard below).
__global__ __launch_bounds__(256) void forces_kernel(
    const float* __restrict__ h_forces,
    const float* __restrict__ V_st,
    const int*   __restrict__ idx_t,
    const float* __restrict__ W_forces,
    const float* __restrict__ b_forces,
    float*       __restrict__ force_out)
{
    const int gid  = blockIdx.x * blockDim.x + threadIdx.x;
    const int wave = gid >> 6;
    const int lane = threadIdx.x & 63;
    const int p    = wave * 2 + (lane >> 5);   // half-wave index
    const int l    = lane & 31;
    if (p >= N_EDGES / 4) return;              // uniform per half-wave
    const int e0 = p * 4;

    const f32x4* w    = reinterpret_cast<const f32x4*>(W_forces);
    const f32x4* base = reinterpret_cast<const f32x4*>(h_forces); // row = 32 x f32x4

    f32x4 b  = w[l];
    f32x4 a0 = __builtin_nontemporal_load(base + (size_t)(e0 + 0) * 32 + l);
    f32x4 a1 = __builtin_nontemporal_load(base + (size_t)(e0 + 1) * 32 + l);
    f32x4 a2 = __builtin_nontemporal_load(base + (size_t)(e0 + 2) * 32 + l);
    f32x4 a3 = __builtin_nontemporal_load(base + (size_t)(e0 + 3) * 32 + l);

    float s0 = dot4(a0, b);
    float s1 = dot4(a1, b);
    float s2 = dot4(a2, b);
    float s3 = dot4(a3, b);

    #pragma unroll
    for (int m = 16; m >= 1; m >>= 1) {
        s0 += __shfl_xor(s0, m, 64);
        s1 += __shfl_xor(s1, m, 64);
        s2 += __shfl_xor(s2, m, 64);
        s3 += __shfl_xor(s3, m, 64);
    }

    const float bias = b_forces[0];

    if (l < 3) {
        // idx_t + e0 is 16B aligned (e0 % 4 == 0)
        const int4 idx4 = *reinterpret_cast<const int4*>(idx_t + e0);
        const float v0 = V_st[(size_t)(e0 + 0) * 3 + l];
        const float v1 = V_st[(size_t)(e0 + 1) * 3 + l];
        const float v2 = V_st[(size_t)(e0 + 2) * 3 + l];
        const float v3 = V_st[(size_t)(e0 + 3) * 3 + l];
        atomicAdd(&force_out[(size_t)idx4.x * 3 + l], (s0 + bias) * v0);
        atomicAdd(&force_out[(size_t)idx4.y * 3 + l], (s1 + bias) * v1);
        atomicAdd(&force_out[(size_t)idx4.z * 3 + l], (s2 + bias) * v2);
        atomicAdd(&force_out[(size_t)idx4.w * 3 + l], (s3 + bias) * v3);
    }
}

extern "C" void kernel_launch(void* const* d_in, const int* in_sizes, int n_in,
                              void* d_out, int out_size, void* d_ws, size_t ws_size,
                              hipStream_t stream) {
    const float* h_energy  = (const float*)d_in[0];
    const float* h_forces  = (const float*)d_in[1];
    const float* V_st      = (const float*)d_in[2];
    const int*   idx_t     = (const int*)d_in[3];
    const int*   batch_idx = (const int*)d_in[4];
    const float* W_energy  = (const float*)d_in[5];
    const float* W_forces  = (const float*)d_in[6];
    const float* b_forces  = (const float*)d_in[7];

    float* y_out     = (float*)d_out;            // N_MOL floats
    float* force_out = (float*)d_out + N_MOL;    // N_ATOMS*3 floats

    // Zero d_out (atomic accumulation needs zeroed output each call).
    const int n4 = out_size / 4;                 // 75250 exactly
    zero_kernel<<<(n4 + 255) / 256, 256, 0, stream>>>((f32x4*)d_out, n4);

    // Forces: 156250 half-waves, 8 per 256-thread block -> 19532 blocks.
    const int fblocks = (N_EDGES / 4 + 7) / 8;   // 19532
    forces_kernel<<<fblocks, 256, 0, stream>>>(
        h_forces, V_st, idx_t, W_forces, b_forces, force_out);

    // Energy: 25000 waves (4 atoms each), 4 waves/block -> 6250 blocks.
    energy_kernel<<<N_ATOMS / 16, 256, 0, stream>>>(h_energy, batch_idx, W_energy, y_out);
}

// Round 8
// 127.473 us; speedup vs baseline: 2.1906x; 1.2618x over previous
//
#include <hip/hip_runtime.h>

#define N_ATOMS 100000
#define N_EDGES 625000
#define N_MOL   1000
#define EMB_ATOM 256
#define EMB_EDGE 128

typedef float f32x4 __attribute__((ext_vector_type(4)));

__device__ __forceinline__ float dot4(f32x4 a, f32x4 b) {
    return a.x * b.x + a.y * b.y + a.z * b.z + a.w * b.w;
}

// Vectorized zero of d_out (301000 floats = 75250 f32x4 exactly).
__global__ __launch_bounds__(256) void zero_kernel(f32x4* __restrict__ p, int n4)
{
    const int i = blockIdx.x * blockDim.x + threadIdx.x;
    if (i < n4) p[i] = (f32x4)(0.f, 0.f, 0.f, 0.f);
}

// Fused kernel. Blocks [0, FBLOCKS) process edges (forces); blocks
// [FBLOCKS, FBLOCKS+EBLOCKS) process atoms (energy).
//
// Forces: 8 lanes per edge row (128 floats). Lane sub (0..7) of slot
// (0..7) loads 4 f32x4 at f32x4-index sub + k*8 (byte offset sub*16 +
// k*128 -> each load instr covers 8 edges x 128B contiguous chunks).
// In-register accumulate over k, then 3-stage butterfly (masks 1,2,4)
// reduces all 8 edges of the wave simultaneously. 2 groups -> 16 edges
// per wave, 8 independent loads (128B/thread) in flight.
//
// Energy: 16 lanes per atom row (256 floats). Lane sub16 loads 4 f32x4
// at sub16 + k*16 (256B contiguous per atom per load). 4-stage butterfly
// (masks 1,2,4,8) reduces 4 atoms at once; 2 groups -> 8 atoms/wave.
#define FWAVES  ((N_EDGES + 15) / 16)            // 39063
#define FBLOCKS ((FWAVES + 3) / 4)               // 9766
#define EBLOCKS (N_ATOMS / 8 / 4)                // 3125 (12500 waves exact)

__global__ __launch_bounds__(256) void fused_kernel(
    const float* __restrict__ h_energy,
    const float* __restrict__ h_forces,
    const float* __restrict__ V_st,
    const int*   __restrict__ idx_t,
    const int*   __restrict__ batch_idx,
    const float* __restrict__ W_energy,
    const float* __restrict__ W_forces,
    const float* __restrict__ b_forces,
    float*       __restrict__ y_out,
    float*       __restrict__ force_out)
{
    const int lane = threadIdx.x & 63;

    if (blockIdx.x < FBLOCKS) {
        // ---------------- forces ----------------
        const int w    = blockIdx.x * 4 + (threadIdx.x >> 6);  // forces wave id
        const int slot = lane >> 3;      // 0..7 : edge slot within wave
        const int sub  = lane & 7;       // 0..7 : position within edge row

        const f32x4* wf   = reinterpret_cast<const f32x4*>(W_forces);
        const f32x4* base = reinterpret_cast<const f32x4*>(h_forces); // row = 32 f32x4

        f32x4 b0 = wf[sub + 0];
        f32x4 b1 = wf[sub + 8];
        f32x4 b2 = wf[sub + 16];
        f32x4 b3 = wf[sub + 24];
        const float bias = b_forces[0];

        #pragma unroll
        for (int g = 0; g < 2; ++g) {
            const int e = w * 16 + g * 8 + slot;
            float s = 0.f;
            if (e < N_EDGES) {
                const f32x4* row = base + (size_t)e * 32;
                f32x4 a0 = __builtin_nontemporal_load(row + sub + 0);
                f32x4 a1 = __builtin_nontemporal_load(row + sub + 8);
                f32x4 a2 = __builtin_nontemporal_load(row + sub + 16);
                f32x4 a3 = __builtin_nontemporal_load(row + sub + 24);
                s = dot4(a0, b0) + dot4(a1, b1) + dot4(a2, b2) + dot4(a3, b3);
            }
            // reduce within each 8-lane slot: all 8 edges of the wave at once
            s += __shfl_xor(s, 1, 64);
            s += __shfl_xor(s, 2, 64);
            s += __shfl_xor(s, 4, 64);

            if (e < N_EDGES && sub < 3) {
                const int   t = idx_t[e];
                const float v = V_st[(size_t)e * 3 + sub];
                atomicAdd(&force_out[(size_t)t * 3 + sub], (s + bias) * v);
            }
        }
    } else if (blockIdx.x < FBLOCKS + EBLOCKS) {
        // ---------------- energy ----------------
        const int w     = (blockIdx.x - FBLOCKS) * 4 + (threadIdx.x >> 6);
        const int slot  = lane >> 4;     // 0..3 : atom slot
        const int sub   = lane & 15;     // 0..15: position within atom row

        const f32x4* we   = reinterpret_cast<const f32x4*>(W_energy);
        const f32x4* base = reinterpret_cast<const f32x4*>(h_energy); // row = 64 f32x4

        f32x4 b0 = we[sub + 0];
        f32x4 b1 = we[sub + 16];
        f32x4 b2 = we[sub + 32];
        f32x4 b3 = we[sub + 48];

        #pragma unroll
        for (int g = 0; g < 2; ++g) {
            const int a = w * 8 + g * 4 + slot;   // < 100000 always (12500 waves exact)
            const f32x4* row = base + (size_t)a * 64;
            f32x4 a0 = __builtin_nontemporal_load(row + sub + 0);
            f32x4 a1 = __builtin_nontemporal_load(row + sub + 16);
            f32x4 a2 = __builtin_nontemporal_load(row + sub + 32);
            f32x4 a3 = __builtin_nontemporal_load(row + sub + 48);
            float s = dot4(a0, b0) + dot4(a1, b1) + dot4(a2, b2) + dot4(a3, b3);

            // reduce within each 16-lane slot: 4 atoms at once
            s += __shfl_xor(s, 1, 64);
            s += __shfl_xor(s, 2, 64);
            s += __shfl_xor(s, 4, 64);
            s += __shfl_xor(s, 8, 64);

            if (sub == 0) atomicAdd(&y_out[batch_idx[a]], s);
        }
    }
}

extern "C" void kernel_launch(void* const* d_in, const int* in_sizes, int n_in,
                              void* d_out, int out_size, void* d_ws, size_t ws_size,
                              hipStream_t stream) {
    const float* h_energy  = (const float*)d_in[0];
    const float* h_forces  = (const float*)d_in[1];
    const float* V_st      = (const float*)d_in[2];
    const int*   idx_t     = (const int*)d_in[3];
    const int*   batch_idx = (const int*)d_in[4];
    const float* W_energy  = (const float*)d_in[5];
    const float* W_forces  = (const float*)d_in[6];
    const float* b_forces  = (const float*)d_in[7];

    float* y_out     = (float*)d_out;            // N_MOL floats
    float* force_out = (float*)d_out + N_MOL;    // N_ATOMS*3 floats

    // Zero d_out (atomic accumulation needs zeroed output each call).
    const int n4 = out_size / 4;                 // 75250 exactly
    zero_kernel<<<(n4 + 255) / 256, 256, 0, stream>>>((f32x4*)d_out, n4);

    // One fused kernel: 9766 forces blocks + 3125 energy blocks.
    fused_kernel<<<FBLOCKS + EBLOCKS, 256, 0, stream>>>(
        h_energy, h_forces, V_st, idx_t, batch_idx,
        W_energy, W_forces, b_forces, y_out, force_out);
}